// Round 5
// baseline (553.207 us; speedup 1.0000x reference)
//
#include <hip/hip_runtime.h>

typedef _Float16 f16;
typedef _Float16 f16x4 __attribute__((ext_vector_type(4)));
typedef _Float16 f16x8 __attribute__((ext_vector_type(8)));
typedef float    f32x4 __attribute__((ext_vector_type(4)));

#define B_ 4
#define C_ 512
#define N_ 4096
#define M_ 64

// Barrier that waits only on LDS ops (lgkmcnt), NOT vmcnt: lets prefetched
// global loads stay in flight across the barrier. sP is double-buffered;
// each wave's ds_reads of buf are drained by its own lgkmcnt(0) one barrier
// before buf is rewritten -> race-free. (Validated round 4: absmax identical.)
__device__ __forceinline__ void barrier_lgkm() {
    asm volatile("s_waitcnt lgkmcnt(0)\n\ts_barrier" ::: "memory");
}

// ---------------------------------------------------------------------------
// Kernel T: x [B][C][N] fp32  ->  x_t [B][N][C] f16   (LDS tile transpose)
// ---------------------------------------------------------------------------
__global__ __launch_bounds__(256) void transpose_cast(
    const float* __restrict__ x, f16* __restrict__ xt)
{
    __shared__ float sT[64][65];
    const int n0 = blockIdx.x * 64;
    const int c0 = blockIdx.y * 64;
    const int b  = blockIdx.z;
    const int tid = threadIdx.x;

    #pragma unroll
    for (int i = 0; i < 16; ++i) {
        int e = i * 256 + tid;
        int c = e >> 6, n = e & 63;
        sT[n][c] = x[((size_t)(b * C_ + c0 + c)) * N_ + (n0 + n)];
    }
    __syncthreads();
    #pragma unroll
    for (int i = 0; i < 16; ++i) {
        int e = i * 256 + tid;
        int n = e >> 6, c = e & 63;
        xt[((size_t)(b * N_ + n0 + n)) * C_ + (c0 + c)] = (f16)sT[n][c];
    }
}

// ---------------------------------------------------------------------------
// Kernel A: fused qkv GEMM, now with distance-1 prefetch of W/xt fragments
// (round-4 post-mortem: serial load->MFMA K-steps exposed L2 latency).
// ---------------------------------------------------------------------------
__global__ __launch_bounds__(512) void qkv_gemm(
    const f16* __restrict__ xt,
    const float* __restrict__ Wq, const float* __restrict__ bq,
    const float* __restrict__ Wk, const float* __restrict__ bk,
    const float* __restrict__ Wv, const float* __restrict__ bv,
    f16* __restrict__ qt, f16* __restrict__ kt, f16* __restrict__ vh)
{
    const int tid  = threadIdx.x;
    const int w    = tid >> 6;
    const int lane = tid & 63;
    const int l15  = lane & 15;
    const int quad = lane >> 4;
    const int nBase = blockIdx.x * 128;
    const int oseg  = blockIdx.y;
    const int b     = blockIdx.z;
    const int ot16  = w & 3;
    const int nhalf = w >> 2;

    const float* Wsel;
    if (oseg == 0)      Wsel = Wq;
    else if (oseg == 1) Wsel = Wk;
    else                Wsel = Wv + (size_t)(oseg - 2) * 64 * C_;

    const int orow = ot16 * 16 + l15;
    const float* wp = Wsel + (size_t)orow * C_ + quad * 8;

    const f16* xrow[4];
    #pragma unroll
    for (int ns = 0; ns < 4; ++ns) {
        int n = nBase + nhalf * 64 + ns * 16 + l15;
        xrow[ns] = xt + ((size_t)(b * N_ + n)) * C_ + quad * 8;
    }

    f32x4 acc[4] = {};

    // preload c0 = 0
    float4 w0c = *(const float4*)(wp);
    float4 w1c = *(const float4*)(wp + 4);
    f16x8 b8c[4];
    #pragma unroll
    for (int ns = 0; ns < 4; ++ns) b8c[ns] = *(const f16x8*)(xrow[ns]);

    for (int c0 = 0; c0 < C_; c0 += 32) {
        float4 w0n, w1n;
        f16x8  b8n[4];
        if (c0 + 32 < C_) {
            w0n = *(const float4*)(wp + c0 + 32);
            w1n = *(const float4*)(wp + c0 + 36);
            #pragma unroll
            for (int ns = 0; ns < 4; ++ns)
                b8n[ns] = *(const f16x8*)(xrow[ns] + c0 + 32);
        }
        f16x8 a8;
        a8[0]=(f16)w0c.x; a8[1]=(f16)w0c.y; a8[2]=(f16)w0c.z; a8[3]=(f16)w0c.w;
        a8[4]=(f16)w1c.x; a8[5]=(f16)w1c.y; a8[6]=(f16)w1c.z; a8[7]=(f16)w1c.w;
        #pragma unroll
        for (int ns = 0; ns < 4; ++ns)
            acc[ns] = __builtin_amdgcn_mfma_f32_16x16x32_f16(a8, b8c[ns], acc[ns], 0, 0, 0);
        w0c = w0n; w1c = w1n;
        #pragma unroll
        for (int ns = 0; ns < 4; ++ns) b8c[ns] = b8n[ns];
    }

    #pragma unroll
    for (int ns = 0; ns < 4; ++ns) {
        int n = nBase + nhalf * 64 + ns * 16 + l15;
        #pragma unroll
        for (int r = 0; r < 4; ++r) {
            int olocal = ot16 * 16 + quad * 4 + r;
            float bias;
            if (oseg == 0)      bias = bq[olocal];
            else if (oseg == 1) bias = bk[olocal];
            else                bias = bv[(oseg - 2) * 64 + olocal];
            f16 h = (f16)(acc[ns][r] + bias);
            if (oseg == 0) {
                qt[((size_t)(b * N_ + n)) * M_ + olocal] = h;
            } else if (oseg == 1) {
                kt[((size_t)(b * N_ + n)) * M_ + olocal] = h;
            } else {
                int c = (oseg - 2) * 64 + olocal;
                vh[((size_t)(b * C_ + c)) * N_ + n] = h;
            }
        }
    }
}

// ---------------------------------------------------------------------------
// Kernel B: two-pass attention, operand-swapped MFMA (round-4 layout).
// Round-5 changes: TI=32, 512 thr (8 waves), grid 512 -> 2 blocks/CU
// (cross-block latency hiding of the barrier convoy); distance-1 k prefetch
// in both passes (score MFMA waits at vmcnt(10), never on a fresh load).
// Scores: wave=(iq=w&1, jq=w>>1 in 0..3). PV: wave owns 64 ch (c0w=w*64).
// ---------------------------------------------------------------------------
#define SP 72   // f16 row stride: 144B, 16B-aligned

__global__ __launch_bounds__(512, 4) void attn(
    const f16* __restrict__ qt, const f16* __restrict__ kt,
    const f16* __restrict__ vh, const float* __restrict__ x,
    const float* __restrict__ gamma, float* __restrict__ out)
{
    __shared__ __align__(16) f16   sP[2][32][SP];   // 9.2 KB
    __shared__ __align__(16) float sRm[4][32];
    __shared__ __align__(16) float sRl[4][32];

    const int tid  = threadIdx.x;
    const int w    = tid >> 6;                      // 0..7
    const int lane = tid & 63;
    const int l15  = lane & 15;
    const int quad = lane >> 4;

    // XCD swizzle: batch pinned to an XCD pair so v (4MB) stays L2-resident
    const int lin  = blockIdx.x;                    // 0..511
    const int b    = (lin & 7) >> 1;
    const int iblk = ((lin >> 3) << 1) | (lin & 1); // 0..127
    const int i0   = iblk * 32;

    const int iq  = w & 1;
    const int jq  = w >> 1;                         // 0..3
    const int c0w = w * 64;                         // PV channel slice

    const size_t kbase = (size_t)b * N_ * M_;
    const f16* kptr = kt + kbase + ((size_t)(jq * 16 + l15)) * M_ + quad * 8;

    // q B-fragments (n = i = iq*16+l15), block-invariant
    f16x8 bqf[2];
    #pragma unroll
    for (int kh = 0; kh < 2; ++kh)
        bqf[kh] = *(const f16x8*)(qt + ((size_t)(b * N_ + i0 + iq * 16 + l15)) * M_
                                  + kh * 32 + quad * 8);

    // ---------------- pass 1: rowmax (registers only, k prefetched) --------
    float mx = -3.0e38f;
    f16x8 akc[2] = { *(const f16x8*)(kptr), *(const f16x8*)(kptr + 32) };
    for (int j0 = 0; j0 < N_; j0 += 64) {
        f16x8 akn[2];
        if (j0 + 64 < N_) {
            const f16* kn = kptr + (size_t)(j0 + 64) * M_;
            akn[0] = *(const f16x8*)(kn);
            akn[1] = *(const f16x8*)(kn + 32);
        }
        f32x4 s = {};
        s = __builtin_amdgcn_mfma_f32_16x16x32_f16(akc[0], bqf[0], s, 0, 0, 0);
        s = __builtin_amdgcn_mfma_f32_16x16x32_f16(akc[1], bqf[1], s, 0, 0, 0);
        mx = fmaxf(mx, fmaxf(fmaxf(s[0], s[1]), fmaxf(s[2], s[3])));
        akc[0] = akn[0]; akc[1] = akn[1];
    }
    mx = fmaxf(mx, __shfl_xor(mx, 16, 64));
    mx = fmaxf(mx, __shfl_xor(mx, 32, 64));
    if (lane < 16) sRm[jq][iq * 16 + l15] = mx;
    barrier_lgkm();
    const int il_s = iq * 16 + l15;
    const float mrow = fmaxf(fmaxf(sRm[0][il_s], sRm[1][il_s]),
                             fmaxf(sRm[2][il_s], sRm[3][il_s]));

    // ---------------- pass 2: P + PV ----------------
    f32x4 acc[4][2] = {};          // [ct][it]: rows c-local, cols i-local
    float l_acc = 0.f;

    akc[0] = *(const f16x8*)(kptr);
    akc[1] = *(const f16x8*)(kptr + 32);

    for (int j0 = 0; j0 < N_; j0 += 64) {
        const int buf = (j0 >> 6) & 1;

        // v loads for THIS tile (consumed after barrier; survive it via lgkm)
        f16x8 vb[4][2];
        #pragma unroll
        for (int ct = 0; ct < 4; ++ct)
            #pragma unroll
            for (int kh = 0; kh < 2; ++kh)
                vb[ct][kh] = *(const f16x8*)(vh + ((size_t)(b * C_ + c0w + ct * 16 + l15)) * N_
                                             + j0 + kh * 32 + quad * 8);
        // k prefetch for NEXT tile
        f16x8 akn[2];
        if (j0 + 64 < N_) {
            const f16* kn = kptr + (size_t)(j0 + 64) * M_;
            akn[0] = *(const f16x8*)(kn);
            akn[1] = *(const f16x8*)(kn + 32);
        }

        // scores with k loaded one tile ago: waits at vmcnt(10)
        f32x4 s = {};
        s = __builtin_amdgcn_mfma_f32_16x16x32_f16(akc[0], bqf[0], s, 0, 0, 0);
        s = __builtin_amdgcn_mfma_f32_16x16x32_f16(akc[1], bqf[1], s, 0, 0, 0);

        f16x4 p4;
        #pragma unroll
        for (int r = 0; r < 4; ++r) {
            float p = __expf(s[r] - mrow);
            l_acc += p;
            p4[r] = (f16)p;
        }
        *(f16x4*)&sP[buf][iq * 16 + l15][jq * 16 + quad * 4] = p4;  // 8B write
        barrier_lgkm();

        // PV: pb = B-frag (n = i = it*16+l15, k = j)
        f16x8 pb[2][2];
        #pragma unroll
        for (int it = 0; it < 2; ++it)
            #pragma unroll
            for (int kh = 0; kh < 2; ++kh)
                pb[it][kh] = *(const f16x8*)&sP[buf][it * 16 + l15][kh * 32 + quad * 8];
        #pragma unroll
        for (int ct = 0; ct < 4; ++ct)
            #pragma unroll
            for (int it = 0; it < 2; ++it)
                #pragma unroll
                for (int kh = 0; kh < 2; ++kh)
                    acc[ct][it] = __builtin_amdgcn_mfma_f32_16x16x32_f16(
                        vb[ct][kh], pb[it][kh], acc[ct][it], 0, 0, 0);

        akc[0] = akn[0]; akc[1] = akn[1];
    }

    // ---------------- l reduction ----------------
    l_acc += __shfl_xor(l_acc, 16, 64);
    l_acc += __shfl_xor(l_acc, 32, 64);
    if (lane < 16) sRl[jq][il_s] = l_acc;
    barrier_lgkm();

    // ---------------- epilogue: out = gamma * feat / l + x ----------------
    const float g = gamma[0];
    #pragma unroll
    for (int it = 0; it < 2; ++it) {
        const int il = it * 16 + l15;
        const float linv = 1.0f / (sRl[0][il] + sRl[1][il] + sRl[2][il] + sRl[3][il]);
        const int i = i0 + il;
        #pragma unroll
        for (int ct = 0; ct < 4; ++ct) {
            #pragma unroll
            for (int r = 0; r < 4; ++r) {
                const int c = c0w + ct * 16 + quad * 4 + r;
                const size_t idx = ((size_t)(b * C_ + c)) * N_ + i;
                out[idx] = g * (acc[ct][it][r] * linv) + x[idx];
            }
        }
    }
}

// ---------------------------------------------------------------------------
extern "C" void kernel_launch(void* const* d_in, const int* in_sizes, int n_in,
                              void* d_out, int out_size, void* d_ws, size_t ws_size,
                              hipStream_t stream)
{
    const float* x     = (const float*)d_in[0];
    const float* Wq    = (const float*)d_in[1];
    const float* bq    = (const float*)d_in[2];
    const float* Wk    = (const float*)d_in[3];
    const float* bk    = (const float*)d_in[4];
    const float* Wv    = (const float*)d_in[5];
    const float* bv    = (const float*)d_in[6];
    const float* gamma = (const float*)d_in[7];
    float* out = (float*)d_out;

    char* ws = (char*)d_ws;
    f16* xt = (f16*)ws;                                   // B*N*C   (16 MB)
    f16* qt = (f16*)(ws + (size_t)B_ * N_ * C_ * 2);      // B*N*M   ( 2 MB)
    f16* kt = qt + (size_t)B_ * N_ * M_;                  // B*N*M   ( 2 MB)
    f16* vh = kt + (size_t)B_ * N_ * M_;                  // B*C*N   (16 MB)

    transpose_cast<<<dim3(N_ / 64, C_ / 64, B_), 256, 0, stream>>>(x, xt);
    qkv_gemm<<<dim3(N_ / 128, 10, B_), 512, 0, stream>>>(
        xt, Wq, bq, Wk, bk, Wv, bv, qt, kt, vh);
    attn<<<dim3(512), 512, 0, stream>>>(qt, kt, vh, x, gamma, out);
}

// Round 6
// 379.097 us; speedup vs baseline: 1.4593x; 1.4593x over previous
//
#include <hip/hip_runtime.h>

typedef _Float16 f16;
typedef _Float16 f16x8 __attribute__((ext_vector_type(8)));
typedef float    f32x4 __attribute__((ext_vector_type(4)));

#define B_ 4
#define C_ 512
#define N_ 4096
#define M_ 64

__device__ __forceinline__ unsigned pk2(float a, float b) {
    union { f16 h[2]; unsigned u; } t;
    t.h[0] = (f16)a; t.h[1] = (f16)b;
    return t.u;
}

// ---------------------------------------------------------------------------
// Kernel T: x [B][C][N] fp32  ->  x_t [B][N][C] f16   (LDS tile transpose)
// ---------------------------------------------------------------------------
__global__ __launch_bounds__(256) void transpose_cast(
    const float* __restrict__ x, f16* __restrict__ xt)
{
    __shared__ float sT[64][65];
    const int n0 = blockIdx.x * 64;
    const int c0 = blockIdx.y * 64;
    const int b  = blockIdx.z;
    const int tid = threadIdx.x;

    #pragma unroll
    for (int i = 0; i < 16; ++i) {
        int e = i * 256 + tid;
        int c = e >> 6, n = e & 63;
        sT[n][c] = x[((size_t)(b * C_ + c0 + c)) * N_ + (n0 + n)];
    }
    __syncthreads();
    #pragma unroll
    for (int i = 0; i < 16; ++i) {
        int e = i * 256 + tid;
        int n = e >> 6, c = e & 63;
        xt[((size_t)(b * N_ + n0 + n)) * C_ + (c0 + c)] = (f16)sT[n][c];
    }
}

// ---------------------------------------------------------------------------
// Kernel A: fused qkv GEMM (round-5 prefetch version). Epilogue now writes
// k and v in MFMA-FRAGMENT ORDER so attn's loads are contiguous 1KB/wave:
//   ktf[b][jt(256)][kh(2)][lane(64)][jj(8)]  (lane = quad*16 + l15; j=jt*16+l15
//        held at m-lanes; element k-index = kh*32+quad*8+jj)
//   vf [b][ct(32)][jb(64)][kh(2)][lane(64)][jj(8)] (c=ct*16+l15; j=jb*64+kh*32+quad*8+jj)
// ---------------------------------------------------------------------------
__global__ __launch_bounds__(512) void qkv_gemm(
    const f16* __restrict__ xt,
    const float* __restrict__ Wq, const float* __restrict__ bq,
    const float* __restrict__ Wk, const float* __restrict__ bk,
    const float* __restrict__ Wv, const float* __restrict__ bv,
    f16* __restrict__ qt, f16* __restrict__ ktf, f16* __restrict__ vf)
{
    const int tid  = threadIdx.x;
    const int w    = tid >> 6;
    const int lane = tid & 63;
    const int l15  = lane & 15;
    const int quad = lane >> 4;
    const int nBase = blockIdx.x * 128;
    const int oseg  = blockIdx.y;
    const int b     = blockIdx.z;
    const int ot16  = w & 3;
    const int nhalf = w >> 2;

    const float* Wsel;
    if (oseg == 0)      Wsel = Wq;
    else if (oseg == 1) Wsel = Wk;
    else                Wsel = Wv + (size_t)(oseg - 2) * 64 * C_;

    const int orow = ot16 * 16 + l15;
    const float* wp = Wsel + (size_t)orow * C_ + quad * 8;

    const f16* xrow[4];
    #pragma unroll
    for (int ns = 0; ns < 4; ++ns) {
        int n = nBase + nhalf * 64 + ns * 16 + l15;
        xrow[ns] = xt + ((size_t)(b * N_ + n)) * C_ + quad * 8;
    }

    f32x4 acc[4] = {};

    float4 w0c = *(const float4*)(wp);
    float4 w1c = *(const float4*)(wp + 4);
    f16x8 b8c[4];
    #pragma unroll
    for (int ns = 0; ns < 4; ++ns) b8c[ns] = *(const f16x8*)(xrow[ns]);

    for (int c0 = 0; c0 < C_; c0 += 32) {
        float4 w0n, w1n;
        f16x8  b8n[4];
        if (c0 + 32 < C_) {
            w0n = *(const float4*)(wp + c0 + 32);
            w1n = *(const float4*)(wp + c0 + 36);
            #pragma unroll
            for (int ns = 0; ns < 4; ++ns)
                b8n[ns] = *(const f16x8*)(xrow[ns] + c0 + 32);
        }
        f16x8 a8;
        a8[0]=(f16)w0c.x; a8[1]=(f16)w0c.y; a8[2]=(f16)w0c.z; a8[3]=(f16)w0c.w;
        a8[4]=(f16)w1c.x; a8[5]=(f16)w1c.y; a8[6]=(f16)w1c.z; a8[7]=(f16)w1c.w;
        #pragma unroll
        for (int ns = 0; ns < 4; ++ns)
            acc[ns] = __builtin_amdgcn_mfma_f32_16x16x32_f16(a8, b8c[ns], acc[ns], 0, 0, 0);
        w0c = w0n; w1c = w1n;
        #pragma unroll
        for (int ns = 0; ns < 4; ++ns) b8c[ns] = b8n[ns];
    }

    #pragma unroll
    for (int ns = 0; ns < 4; ++ns) {
        int n = nBase + nhalf * 64 + ns * 16 + l15;
        #pragma unroll
        for (int r = 0; r < 4; ++r) {
            int olocal = ot16 * 16 + quad * 4 + r;
            float bias;
            if (oseg == 0)      bias = bq[olocal];
            else if (oseg == 1) bias = bk[olocal];
            else                bias = bv[(oseg - 2) * 64 + olocal];
            f16 h = (f16)(acc[ns][r] + bias);
            if (oseg == 0) {
                qt[((size_t)(b * N_ + n)) * M_ + olocal] = h;
            } else if (oseg == 1) {
                // fragment order: jt=n>>4, kh=o>>5, quad=(o>>3)&3, l15=n&15, jj=o&7
                size_t idx = (((size_t)b * 256 + (n >> 4)) * 2 + (olocal >> 5)) * 512
                           + (size_t)((((olocal >> 3) & 3) * 16 + (n & 15)) * 8) + (olocal & 7);
                ktf[idx] = h;
            } else {
                int c = (oseg - 2) * 64 + olocal;
                // ct=c>>4, jb=n>>6, kh=(n>>5)&1, quad=(n>>3)&3, l15=c&15, jj=n&7
                size_t idx = ((size_t)b * (C_ * N_)) + (size_t)(c >> 4) * 65536
                           + (size_t)(n >> 6) * 1024 + (size_t)((n >> 5) & 1) * 512
                           + (size_t)((((n >> 3) & 3) * 16 + (c & 15)) * 8) + (n & 7);
                vf[idx] = h;
            }
        }
    }
}

// ---------------------------------------------------------------------------
// Kernel B: BARRIER-FREE, LDS-FREE fused attention.
// Block: 256 thr = 4 waves. Each wave: i-slice [i0,i0+32), c-slice w*128..+128,
// loops ALL j. Scores computed per-wave (4x c-duplication of QK^T — cheap).
// Pass 1: register rowmax (2 shfl_xor at end). Pass 2: exp, in-register
// C-layout -> B-frag reshuffle of P (ds_bpermute, no LDS), PV MFMA.
// All k/v fragment loads are contiguous 1KB (fragment-order layouts).
// ---------------------------------------------------------------------------
__global__ __launch_bounds__(256, 2) void attn(
    const f16* __restrict__ qt, const f16* __restrict__ ktf,
    const f16* __restrict__ vf, const float* __restrict__ x,
    const float* __restrict__ gamma, float* __restrict__ out)
{
    const int tid  = threadIdx.x;
    const int w    = tid >> 6;                  // 0..3
    const int lane = tid & 63;
    const int l15  = lane & 15;
    const int quad = lane >> 4;

    // XCD swizzle: batch pinned to an XCD pair so v (4MB) stays L2-resident
    const int lin  = blockIdx.x;                // 0..511
    const int b    = (lin & 7) >> 1;
    const int iblk = ((lin >> 3) << 1) | (lin & 1);
    const int i0   = iblk * 32;
    const int ctg0 = w * 8;                     // 16-ch tile base (c0 = w*128)

    const f16* kln = ktf + (size_t)b * (N_ * M_) + lane * 8;
    const f16* vln = vf  + (size_t)b * (C_ * N_) + lane * 8;

    // q B-fragments (n=i=l15), block-invariant (one-time 16-seg loads)
    f16x8 bqf[2][2];
    #pragma unroll
    for (int is = 0; is < 2; ++is)
        #pragma unroll
        for (int kh = 0; kh < 2; ++kh)
            bqf[is][kh] = *(const f16x8*)(qt + ((size_t)(b * N_ + i0 + is * 16 + l15)) * M_
                                          + kh * 32 + quad * 8);

    // ---------------- pass 1: rowmax, registers only ----------------
    float mx0 = -3.0e38f, mx1 = -3.0e38f;
    f16x8 akc[4][2];
    #pragma unroll
    for (int jt = 0; jt < 4; ++jt)
        #pragma unroll
        for (int kh = 0; kh < 2; ++kh)
            akc[jt][kh] = *(const f16x8*)(kln + (size_t)jt * 1024 + kh * 512);

    #pragma unroll 2
    for (int j0 = 0; j0 < N_; j0 += 64) {
        f16x8 akn[4][2];
        if (j0 + 64 < N_) {
            const f16* kn = kln + (size_t)(j0 + 64) * 64;   // (j0/16)*1024
            #pragma unroll
            for (int jt = 0; jt < 4; ++jt)
                #pragma unroll
                for (int kh = 0; kh < 2; ++kh)
                    akn[jt][kh] = *(const f16x8*)(kn + (size_t)jt * 1024 + kh * 512);
        }
        #pragma unroll
        for (int jt = 0; jt < 4; ++jt) {
            f32x4 s0 = {}, s1 = {};
            s0 = __builtin_amdgcn_mfma_f32_16x16x32_f16(akc[jt][0], bqf[0][0], s0, 0, 0, 0);
            s0 = __builtin_amdgcn_mfma_f32_16x16x32_f16(akc[jt][1], bqf[0][1], s0, 0, 0, 0);
            s1 = __builtin_amdgcn_mfma_f32_16x16x32_f16(akc[jt][0], bqf[1][0], s1, 0, 0, 0);
            s1 = __builtin_amdgcn_mfma_f32_16x16x32_f16(akc[jt][1], bqf[1][1], s1, 0, 0, 0);
            mx0 = fmaxf(mx0, fmaxf(fmaxf(s0[0], s0[1]), fmaxf(s0[2], s0[3])));
            mx1 = fmaxf(mx1, fmaxf(fmaxf(s1[0], s1[1]), fmaxf(s1[2], s1[3])));
        }
        #pragma unroll
        for (int jt = 0; jt < 4; ++jt)
            #pragma unroll
            for (int kh = 0; kh < 2; ++kh)
                akc[jt][kh] = akn[jt][kh];
    }
    // lane covers rows j = quad*4+r only -> reduce over quads (i stays in l15)
    mx0 = fmaxf(mx0, __shfl_xor(mx0, 16, 64));
    mx0 = fmaxf(mx0, __shfl_xor(mx0, 32, 64));
    mx1 = fmaxf(mx1, __shfl_xor(mx1, 16, 64));
    mx1 = fmaxf(mx1, __shfl_xor(mx1, 32, 64));

    // ---------------- pass 2: P + PV ----------------
    f32x4 acc[8][2] = {};      // [ct][is]; rows=c-local(quad*4+r), cols=i(l15)
    float l0 = 0.f, l1 = 0.f;

    #pragma unroll
    for (int jt = 0; jt < 4; ++jt)
        #pragma unroll
        for (int kh = 0; kh < 2; ++kh)
            akc[jt][kh] = *(const f16x8*)(kln + (size_t)jt * 1024 + kh * 512);

    const int src0 = ((quad & 1) * 2) * 16 + l15;   // bpermute source lanes
    const int src1 = src0 + 16;
    const bool hi  = (quad >= 2);

    #pragma unroll 2
    for (int j0 = 0; j0 < N_; j0 += 64) {
        const f16* vt = vln + (size_t)(j0 >> 6) * 1024;
        // v kh0 loads early (consumed after softmax -> latency covered)
        f16x8 vb0[8];
        #pragma unroll
        for (int ct = 0; ct < 8; ++ct)
            vb0[ct] = *(const f16x8*)(vt + (size_t)(ctg0 + ct) * 65536);
        // k prefetch for next iter
        f16x8 akn[4][2];
        if (j0 + 64 < N_) {
            const f16* kn = kln + (size_t)(j0 + 64) * 64;
            #pragma unroll
            for (int jt = 0; jt < 4; ++jt)
                #pragma unroll
                for (int kh = 0; kh < 2; ++kh)
                    akn[jt][kh] = *(const f16x8*)(kn + (size_t)jt * 1024 + kh * 512);
        }

        // scores -> p (f16 packed pairs), per-lane l accumulation
        unsigned pkd[2][4][2];
        #pragma unroll
        for (int jt = 0; jt < 4; ++jt) {
            f32x4 s0 = {}, s1 = {};
            s0 = __builtin_amdgcn_mfma_f32_16x16x32_f16(akc[jt][0], bqf[0][0], s0, 0, 0, 0);
            s0 = __builtin_amdgcn_mfma_f32_16x16x32_f16(akc[jt][1], bqf[0][1], s0, 0, 0, 0);
            s1 = __builtin_amdgcn_mfma_f32_16x16x32_f16(akc[jt][0], bqf[1][0], s1, 0, 0, 0);
            s1 = __builtin_amdgcn_mfma_f32_16x16x32_f16(akc[jt][1], bqf[1][1], s1, 0, 0, 0);
            float p0 = __expf(s0[0] - mx0), p1 = __expf(s0[1] - mx0);
            float p2 = __expf(s0[2] - mx0), p3 = __expf(s0[3] - mx0);
            l0 += (p0 + p1) + (p2 + p3);
            pkd[0][jt][0] = pk2(p0, p1); pkd[0][jt][1] = pk2(p2, p3);
            float q0 = __expf(s1[0] - mx1), q1 = __expf(s1[1] - mx1);
            float q2 = __expf(s1[2] - mx1), q3 = __expf(s1[3] - mx1);
            l1 += (q0 + q1) + (q2 + q3);
            pkd[1][jt][0] = pk2(q0, q1); pkd[1][jt][1] = pk2(q2, q3);
        }

        // C-layout -> B-frag reshuffle (quad-level j permute; i stays at l15)
        f16x8 pbf[2][2];
        #pragma unroll
        for (int is = 0; is < 2; ++is)
            #pragma unroll
            for (int kh = 0; kh < 2; ++kh) {
                unsigned a0 = __shfl((int)pkd[is][kh * 2][0],     src0, 64);
                unsigned b0 = __shfl((int)pkd[is][kh * 2 + 1][0], src0, 64);
                unsigned a1 = __shfl((int)pkd[is][kh * 2][1],     src0, 64);
                unsigned b1 = __shfl((int)pkd[is][kh * 2 + 1][1], src0, 64);
                unsigned a2 = __shfl((int)pkd[is][kh * 2][0],     src1, 64);
                unsigned b2 = __shfl((int)pkd[is][kh * 2 + 1][0], src1, 64);
                unsigned a3 = __shfl((int)pkd[is][kh * 2][1],     src1, 64);
                unsigned b3 = __shfl((int)pkd[is][kh * 2 + 1][1], src1, 64);
                union { unsigned u[4]; f16x8 v; } U;
                U.u[0] = hi ? b0 : a0;
                U.u[1] = hi ? b1 : a1;
                U.u[2] = hi ? b2 : a2;
                U.u[3] = hi ? b3 : a3;
                pbf[is][kh] = U.v;
            }

        // v kh1 loads (latency behind PV kh0)
        f16x8 vb1[8];
        #pragma unroll
        for (int ct = 0; ct < 8; ++ct)
            vb1[ct] = *(const f16x8*)(vt + (size_t)(ctg0 + ct) * 65536 + 512);

        #pragma unroll
        for (int ct = 0; ct < 8; ++ct) {
            acc[ct][0] = __builtin_amdgcn_mfma_f32_16x16x32_f16(vb0[ct], pbf[0][0], acc[ct][0], 0, 0, 0);
            acc[ct][1] = __builtin_amdgcn_mfma_f32_16x16x32_f16(vb0[ct], pbf[1][0], acc[ct][1], 0, 0, 0);
        }
        #pragma unroll
        for (int ct = 0; ct < 8; ++ct) {
            acc[ct][0] = __builtin_amdgcn_mfma_f32_16x16x32_f16(vb1[ct], pbf[0][1], acc[ct][0], 0, 0, 0);
            acc[ct][1] = __builtin_amdgcn_mfma_f32_16x16x32_f16(vb1[ct], pbf[1][1], acc[ct][1], 0, 0, 0);
        }

        #pragma unroll
        for (int jt = 0; jt < 4; ++jt)
            #pragma unroll
            for (int kh = 0; kh < 2; ++kh)
                akc[jt][kh] = akn[jt][kh];
    }

    // per-lane l covers quad's j rows only -> reduce over quads
    l0 += __shfl_xor(l0, 16, 64);
    l0 += __shfl_xor(l0, 32, 64);
    l1 += __shfl_xor(l1, 16, 64);
    l1 += __shfl_xor(l1, 32, 64);

    // ---------------- epilogue: out = gamma * feat / l + x ----------------
    const float g = gamma[0];
    const float linv0 = 1.0f / l0, linv1 = 1.0f / l1;
    #pragma unroll
    for (int is = 0; is < 2; ++is) {
        const float li = is ? linv1 : linv0;
        const int i = i0 + is * 16 + l15;
        #pragma unroll
        for (int ct = 0; ct < 8; ++ct) {
            #pragma unroll
            for (int r = 0; r < 4; ++r) {
                const int c = (ctg0 + ct) * 16 + quad * 4 + r;
                const size_t idx = ((size_t)(b * C_ + c)) * N_ + i;
                out[idx] = g * (acc[ct][is][r] * li) + x[idx];
            }
        }
    }
}

// ---------------------------------------------------------------------------
extern "C" void kernel_launch(void* const* d_in, const int* in_sizes, int n_in,
                              void* d_out, int out_size, void* d_ws, size_t ws_size,
                              hipStream_t stream)
{
    const float* x     = (const float*)d_in[0];
    const float* Wq    = (const float*)d_in[1];
    const float* bq    = (const float*)d_in[2];
    const float* Wk    = (const float*)d_in[3];
    const float* bk    = (const float*)d_in[4];
    const float* Wv    = (const float*)d_in[5];
    const float* bv    = (const float*)d_in[6];
    const float* gamma = (const float*)d_in[7];
    float* out = (float*)d_out;

    char* ws = (char*)d_ws;
    f16* xt  = (f16*)ws;                                   // B*N*C   (16 MB)
    f16* qt  = (f16*)(ws + (size_t)B_ * N_ * C_ * 2);      // B*N*M   ( 2 MB)
    f16* ktf = qt + (size_t)B_ * N_ * M_;                  // B*N*M   ( 2 MB)
    f16* vf  = ktf + (size_t)B_ * N_ * M_;                 // B*C*N   (16 MB)

    transpose_cast<<<dim3(N_ / 64, C_ / 64, B_), 256, 0, stream>>>(x, xt);
    qkv_gemm<<<dim3(N_ / 128, 10, B_), 512, 0, stream>>>(
        xt, Wq, bq, Wk, bk, Wv, bv, qt, ktf, vf);
    attn<<<dim3(512), 256, 0, stream>>>(qt, ktf, vf, x, gamma, out);
}

// Round 7
// 330.301 us; speedup vs baseline: 1.6749x; 1.1477x over previous
//
#include <hip/hip_runtime.h>

typedef _Float16 f16;
typedef _Float16 f16x8 __attribute__((ext_vector_type(8)));
typedef float    f32x4 __attribute__((ext_vector_type(4)));

#define B_ 4
#define C_ 512
#define N_ 4096
#define M_ 64

__device__ __forceinline__ unsigned pk2(float a, float b) {
    union { f16 h[2]; unsigned u; } t;
    t.h[0] = (f16)a; t.h[1] = (f16)b;
    return t.u;
}

// ---------------------------------------------------------------------------
// Kernel T: x [B][C][N] fp32 -> xtf in qkv B-FRAGMENT ORDER:
//   xtf[b][nt(256)][ck(16)][lane(64)][jj(8)], n = nt*16 + (lane&15),
//   c = ck*32 + (lane>>4)*8 + jj.
// LDS tile 64c x 64n, row stride 65 (phase-1 writes 2-way banked, phase-2
// reads 2-way banked — both free per m136). Stores: 16B/lane, 1KB/wave.
// ---------------------------------------------------------------------------
__global__ __launch_bounds__(256) void transpose_cast(
    const float* __restrict__ x, f16* __restrict__ xtf)
{
    __shared__ float sT[64][65];
    const int n0 = blockIdx.x * 64;
    const int c0 = blockIdx.y * 64;
    const int b  = blockIdx.z;
    const int tid = threadIdx.x;

    #pragma unroll
    for (int i = 0; i < 4; ++i) {
        int e = i * 256 + tid;
        int c = e >> 4;              // 0..63
        int n4 = (e & 15) * 4;       // 0..60, lanes consecutive -> coalesced 16B
        float4 v = *(const float4*)(x + ((size_t)(b * C_ + c0 + c)) * N_ + n0 + n4);
        sT[c][n4 + 0] = v.x; sT[c][n4 + 1] = v.y;
        sT[c][n4 + 2] = v.z; sT[c][n4 + 3] = v.w;
    }
    __syncthreads();

    const int w = tid >> 6, lane = tid & 63, l15 = lane & 15, quad = lane >> 4;
    #pragma unroll
    for (int j = 0; j < 2; ++j) {
        const int fb  = w * 2 + j;        // 0..7: (lnt 0..3) x (lck 0..1)
        const int lnt = fb >> 1, lck = fb & 1;
        const int nl  = lnt * 16 + l15;
        const int cb  = lck * 32 + quad * 8;
        f16x8 o;
        #pragma unroll
        for (int jj = 0; jj < 8; ++jj) o[jj] = (f16)sT[cb + jj][nl];
        const int ntg = (n0 >> 4) + lnt;
        const int ck  = (c0 >> 5) + lck;
        size_t idx = (((size_t)(b * 256 + ntg)) * 16 + ck) * 512 + lane * 8;
        *(f16x8*)(xtf + idx) = o;
    }
}

// ---------------------------------------------------------------------------
// Kernel A: fused qkv GEMM. B-operand now loaded CONTIGUOUSLY from xtf
// (1 segment vs 16). W fp32 scatter remains (L2-hot: reused 128x).
// Epilogue identical to round 6 (validated): q row-major, k/v fragment-order.
// ---------------------------------------------------------------------------
__global__ __launch_bounds__(512) void qkv_gemm(
    const f16* __restrict__ xtf,
    const float* __restrict__ Wq, const float* __restrict__ bq,
    const float* __restrict__ Wk, const float* __restrict__ bk,
    const float* __restrict__ Wv, const float* __restrict__ bv,
    f16* __restrict__ qt, f16* __restrict__ ktf, f16* __restrict__ vf)
{
    const int tid  = threadIdx.x;
    const int w    = tid >> 6;
    const int lane = tid & 63;
    const int l15  = lane & 15;
    const int quad = lane >> 4;
    const int nBase = blockIdx.x * 128;
    const int oseg  = blockIdx.y;
    const int b     = blockIdx.z;
    const int ot16  = w & 3;
    const int nhalf = w >> 2;

    const float* Wsel;
    if (oseg == 0)      Wsel = Wq;
    else if (oseg == 1) Wsel = Wk;
    else                Wsel = Wv + (size_t)(oseg - 2) * 64 * C_;

    const int orow = ot16 * 16 + l15;
    const float* wp = Wsel + (size_t)orow * C_ + quad * 8;

    // fragment-order B pointers: one contiguous 1KB block per (ns, ck)
    const f16* xfb[4];
    #pragma unroll
    for (int ns = 0; ns < 4; ++ns) {
        int ntg = (nBase >> 4) + nhalf * 4 + ns;
        xfb[ns] = xtf + (((size_t)(b * 256 + ntg)) * 16) * 512 + lane * 8;
    }

    f32x4 acc[4] = {};

    float4 w0c = *(const float4*)(wp);
    float4 w1c = *(const float4*)(wp + 4);
    f16x8 b8c[4];
    #pragma unroll
    for (int ns = 0; ns < 4; ++ns) b8c[ns] = *(const f16x8*)(xfb[ns]);

    for (int ck = 0; ck < 16; ++ck) {
        float4 w0n, w1n;
        f16x8  b8n[4];
        if (ck + 1 < 16) {
            w0n = *(const float4*)(wp + ck * 32 + 32);
            w1n = *(const float4*)(wp + ck * 32 + 36);
            #pragma unroll
            for (int ns = 0; ns < 4; ++ns)
                b8n[ns] = *(const f16x8*)(xfb[ns] + (ck + 1) * 512);
        }
        f16x8 a8;
        a8[0]=(f16)w0c.x; a8[1]=(f16)w0c.y; a8[2]=(f16)w0c.z; a8[3]=(f16)w0c.w;
        a8[4]=(f16)w1c.x; a8[5]=(f16)w1c.y; a8[6]=(f16)w1c.z; a8[7]=(f16)w1c.w;
        #pragma unroll
        for (int ns = 0; ns < 4; ++ns)
            acc[ns] = __builtin_amdgcn_mfma_f32_16x16x32_f16(a8, b8c[ns], acc[ns], 0, 0, 0);
        w0c = w0n; w1c = w1n;
        #pragma unroll
        for (int ns = 0; ns < 4; ++ns) b8c[ns] = b8n[ns];
    }

    #pragma unroll
    for (int ns = 0; ns < 4; ++ns) {
        int n = nBase + nhalf * 64 + ns * 16 + l15;
        #pragma unroll
        for (int r = 0; r < 4; ++r) {
            int olocal = ot16 * 16 + quad * 4 + r;
            float bias;
            if (oseg == 0)      bias = bq[olocal];
            else if (oseg == 1) bias = bk[olocal];
            else                bias = bv[(oseg - 2) * 64 + olocal];
            f16 h = (f16)(acc[ns][r] + bias);
            if (oseg == 0) {
                qt[((size_t)(b * N_ + n)) * M_ + olocal] = h;
            } else if (oseg == 1) {
                size_t idx = (((size_t)b * 256 + (n >> 4)) * 2 + (olocal >> 5)) * 512
                           + (size_t)((((olocal >> 3) & 3) * 16 + (n & 15)) * 8) + (olocal & 7);
                ktf[idx] = h;
            } else {
                int c = (oseg - 2) * 64 + olocal;
                size_t idx = ((size_t)b * (C_ * N_)) + (size_t)(c >> 4) * 65536
                           + (size_t)(n >> 6) * 1024 + (size_t)((n >> 5) & 1) * 512
                           + (size_t)((((n >> 3) & 3) * 16 + (c & 15)) * 8) + (n & 7);
                vf[idx] = h;
            }
        }
    }
}

// ---------------------------------------------------------------------------
// Kernel B: BARRIER-FREE, LDS-FREE fused attention. (round-6, validated —
// unchanged this round; MfmaUtil 29%/VALU 40% measured)
// ---------------------------------------------------------------------------
__global__ __launch_bounds__(256, 2) void attn(
    const f16* __restrict__ qt, const f16* __restrict__ ktf,
    const f16* __restrict__ vf, const float* __restrict__ x,
    const float* __restrict__ gamma, float* __restrict__ out)
{
    const int tid  = threadIdx.x;
    const int w    = tid >> 6;                  // 0..3
    const int lane = tid & 63;
    const int l15  = lane & 15;
    const int quad = lane >> 4;

    const int lin  = blockIdx.x;                // 0..511
    const int b    = (lin & 7) >> 1;
    const int iblk = ((lin >> 3) << 1) | (lin & 1);
    const int i0   = iblk * 32;
    const int ctg0 = w * 8;

    const f16* kln = ktf + (size_t)b * (N_ * M_) + lane * 8;
    const f16* vln = vf  + (size_t)b * (C_ * N_) + lane * 8;

    f16x8 bqf[2][2];
    #pragma unroll
    for (int is = 0; is < 2; ++is)
        #pragma unroll
        for (int kh = 0; kh < 2; ++kh)
            bqf[is][kh] = *(const f16x8*)(qt + ((size_t)(b * N_ + i0 + is * 16 + l15)) * M_
                                          + kh * 32 + quad * 8);

    // ---------------- pass 1: rowmax, registers only ----------------
    float mx0 = -3.0e38f, mx1 = -3.0e38f;
    f16x8 akc[4][2];
    #pragma unroll
    for (int jt = 0; jt < 4; ++jt)
        #pragma unroll
        for (int kh = 0; kh < 2; ++kh)
            akc[jt][kh] = *(const f16x8*)(kln + (size_t)jt * 1024 + kh * 512);

    #pragma unroll 2
    for (int j0 = 0; j0 < N_; j0 += 64) {
        f16x8 akn[4][2];
        if (j0 + 64 < N_) {
            const f16* kn = kln + (size_t)(j0 + 64) * 64;
            #pragma unroll
            for (int jt = 0; jt < 4; ++jt)
                #pragma unroll
                for (int kh = 0; kh < 2; ++kh)
                    akn[jt][kh] = *(const f16x8*)(kn + (size_t)jt * 1024 + kh * 512);
        }
        #pragma unroll
        for (int jt = 0; jt < 4; ++jt) {
            f32x4 s0 = {}, s1 = {};
            s0 = __builtin_amdgcn_mfma_f32_16x16x32_f16(akc[jt][0], bqf[0][0], s0, 0, 0, 0);
            s0 = __builtin_amdgcn_mfma_f32_16x16x32_f16(akc[jt][1], bqf[0][1], s0, 0, 0, 0);
            s1 = __builtin_amdgcn_mfma_f32_16x16x32_f16(akc[jt][0], bqf[1][0], s1, 0, 0, 0);
            s1 = __builtin_amdgcn_mfma_f32_16x16x32_f16(akc[jt][1], bqf[1][1], s1, 0, 0, 0);
            mx0 = fmaxf(mx0, fmaxf(fmaxf(s0[0], s0[1]), fmaxf(s0[2], s0[3])));
            mx1 = fmaxf(mx1, fmaxf(fmaxf(s1[0], s1[1]), fmaxf(s1[2], s1[3])));
        }
        #pragma unroll
        for (int jt = 0; jt < 4; ++jt)
            #pragma unroll
            for (int kh = 0; kh < 2; ++kh)
                akc[jt][kh] = akn[jt][kh];
    }
    mx0 = fmaxf(mx0, __shfl_xor(mx0, 16, 64));
    mx0 = fmaxf(mx0, __shfl_xor(mx0, 32, 64));
    mx1 = fmaxf(mx1, __shfl_xor(mx1, 16, 64));
    mx1 = fmaxf(mx1, __shfl_xor(mx1, 32, 64));

    // ---------------- pass 2: P + PV ----------------
    f32x4 acc[8][2] = {};
    float l0 = 0.f, l1 = 0.f;

    #pragma unroll
    for (int jt = 0; jt < 4; ++jt)
        #pragma unroll
        for (int kh = 0; kh < 2; ++kh)
            akc[jt][kh] = *(const f16x8*)(kln + (size_t)jt * 1024 + kh * 512);

    const int src0 = ((quad & 1) * 2) * 16 + l15;
    const int src1 = src0 + 16;
    const bool hi  = (quad >= 2);

    #pragma unroll 2
    for (int j0 = 0; j0 < N_; j0 += 64) {
        const f16* vt = vln + (size_t)(j0 >> 6) * 1024;
        f16x8 vb0[8];
        #pragma unroll
        for (int ct = 0; ct < 8; ++ct)
            vb0[ct] = *(const f16x8*)(vt + (size_t)(ctg0 + ct) * 65536);
        f16x8 akn[4][2];
        if (j0 + 64 < N_) {
            const f16* kn = kln + (size_t)(j0 + 64) * 64;
            #pragma unroll
            for (int jt = 0; jt < 4; ++jt)
                #pragma unroll
                for (int kh = 0; kh < 2; ++kh)
                    akn[jt][kh] = *(const f16x8*)(kn + (size_t)jt * 1024 + kh * 512);
        }

        unsigned pkd[2][4][2];
        #pragma unroll
        for (int jt = 0; jt < 4; ++jt) {
            f32x4 s0 = {}, s1 = {};
            s0 = __builtin_amdgcn_mfma_f32_16x16x32_f16(akc[jt][0], bqf[0][0], s0, 0, 0, 0);
            s0 = __builtin_amdgcn_mfma_f32_16x16x32_f16(akc[jt][1], bqf[0][1], s0, 0, 0, 0);
            s1 = __builtin_amdgcn_mfma_f32_16x16x32_f16(akc[jt][0], bqf[1][0], s1, 0, 0, 0);
            s1 = __builtin_amdgcn_mfma_f32_16x16x32_f16(akc[jt][1], bqf[1][1], s1, 0, 0, 0);
            float p0 = __expf(s0[0] - mx0), p1 = __expf(s0[1] - mx0);
            float p2 = __expf(s0[2] - mx0), p3 = __expf(s0[3] - mx0);
            l0 += (p0 + p1) + (p2 + p3);
            pkd[0][jt][0] = pk2(p0, p1); pkd[0][jt][1] = pk2(p2, p3);
            float q0 = __expf(s1[0] - mx1), q1 = __expf(s1[1] - mx1);
            float q2 = __expf(s1[2] - mx1), q3 = __expf(s1[3] - mx1);
            l1 += (q0 + q1) + (q2 + q3);
            pkd[1][jt][0] = pk2(q0, q1); pkd[1][jt][1] = pk2(q2, q3);
        }

        f16x8 pbf[2][2];
        #pragma unroll
        for (int is = 0; is < 2; ++is)
            #pragma unroll
            for (int kh = 0; kh < 2; ++kh) {
                unsigned a0 = __shfl((int)pkd[is][kh * 2][0],     src0, 64);
                unsigned b0 = __shfl((int)pkd[is][kh * 2 + 1][0], src0, 64);
                unsigned a1 = __shfl((int)pkd[is][kh * 2][1],     src0, 64);
                unsigned b1 = __shfl((int)pkd[is][kh * 2 + 1][1], src0, 64);
                unsigned a2 = __shfl((int)pkd[is][kh * 2][0],     src1, 64);
                unsigned b2 = __shfl((int)pkd[is][kh * 2 + 1][0], src1, 64);
                unsigned a3 = __shfl((int)pkd[is][kh * 2][1],     src1, 64);
                unsigned b3 = __shfl((int)pkd[is][kh * 2 + 1][1], src1, 64);
                union { unsigned u[4]; f16x8 v; } U;
                U.u[0] = hi ? b0 : a0;
                U.u[1] = hi ? b1 : a1;
                U.u[2] = hi ? b2 : a2;
                U.u[3] = hi ? b3 : a3;
                pbf[is][kh] = U.v;
            }

        f16x8 vb1[8];
        #pragma unroll
        for (int ct = 0; ct < 8; ++ct)
            vb1[ct] = *(const f16x8*)(vt + (size_t)(ctg0 + ct) * 65536 + 512);

        #pragma unroll
        for (int ct = 0; ct < 8; ++ct) {
            acc[ct][0] = __builtin_amdgcn_mfma_f32_16x16x32_f16(vb0[ct], pbf[0][0], acc[ct][0], 0, 0, 0);
            acc[ct][1] = __builtin_amdgcn_mfma_f32_16x16x32_f16(vb0[ct], pbf[1][0], acc[ct][1], 0, 0, 0);
        }
        #pragma unroll
        for (int ct = 0; ct < 8; ++ct) {
            acc[ct][0] = __builtin_amdgcn_mfma_f32_16x16x32_f16(vb1[ct], pbf[0][1], acc[ct][0], 0, 0, 0);
            acc[ct][1] = __builtin_amdgcn_mfma_f32_16x16x32_f16(vb1[ct], pbf[1][1], acc[ct][1], 0, 0, 0);
        }

        #pragma unroll
        for (int jt = 0; jt < 4; ++jt)
            #pragma unroll
            for (int kh = 0; kh < 2; ++kh)
                akc[jt][kh] = akn[jt][kh];
    }

    l0 += __shfl_xor(l0, 16, 64);
    l0 += __shfl_xor(l0, 32, 64);
    l1 += __shfl_xor(l1, 16, 64);
    l1 += __shfl_xor(l1, 32, 64);

    const float g = gamma[0];
    const float linv0 = 1.0f / l0, linv1 = 1.0f / l1;
    #pragma unroll
    for (int is = 0; is < 2; ++is) {
        const float li = is ? linv1 : linv0;
        const int i = i0 + is * 16 + l15;
        #pragma unroll
        for (int ct = 0; ct < 8; ++ct) {
            #pragma unroll
            for (int r = 0; r < 4; ++r) {
                const int c = (ctg0 + ct) * 16 + quad * 4 + r;
                const size_t idx = ((size_t)(b * C_ + c)) * N_ + i;
                out[idx] = g * (acc[ct][is][r] * li) + x[idx];
            }
        }
    }
}

// ---------------------------------------------------------------------------
extern "C" void kernel_launch(void* const* d_in, const int* in_sizes, int n_in,
                              void* d_out, int out_size, void* d_ws, size_t ws_size,
                              hipStream_t stream)
{
    const float* x     = (const float*)d_in[0];
    const float* Wq    = (const float*)d_in[1];
    const float* bq    = (const float*)d_in[2];
    const float* Wk    = (const float*)d_in[3];
    const float* bk    = (const float*)d_in[4];
    const float* Wv    = (const float*)d_in[5];
    const float* bv    = (const float*)d_in[6];
    const float* gamma = (const float*)d_in[7];
    float* out = (float*)d_out;

    char* ws = (char*)d_ws;
    f16* xtf = (f16*)ws;                                   // B*N*C   (16 MB)
    f16* qt  = (f16*)(ws + (size_t)B_ * N_ * C_ * 2);      // B*N*M   ( 2 MB)
    f16* ktf = qt + (size_t)B_ * N_ * M_;                  // B*N*M   ( 2 MB)
    f16* vf  = ktf + (size_t)B_ * N_ * M_;                 // B*C*N   (16 MB)

    transpose_cast<<<dim3(N_ / 64, C_ / 64, B_), 256, 0, stream>>>(x, xtf);
    qkv_gemm<<<dim3(N_ / 128, 10, B_), 512, 0, stream>>>(
        xtf, Wq, bq, Wk, bk, Wv, bv, qt, ktf, vf);
    attn<<<dim3(512), 256, 0, stream>>>(qt, ktf, vf, x, gamma, out);
}